// Round 10
// baseline (182.004 us; speedup 1.0000x reference)
//
#include <hip/hip_runtime.h>

// sparselinear: out[b*S + s] = sum_{e: row[e]==s} x[b*G + col[e]] * W[e] + bias[s]
// B=64 (== wavefront), G=20000, S=200000, NNZ=2e6.
//
// R9 post-mortem: raising occupancy (27->17.4KB LDS, 48->56%) REGRESSED
// compute 65.7->76.4us => F-loop is VALU-ISSUE bound (5 VALU/edge * 2e6
// edges * 2cyc / 256CU ~= 33us = VALUBusy 50% of 65.7us). Reverted the
// R9 epilogue. R10: halve per-edge instructions via HALF-WAVE PAIRING:
// lanes 0-31 take edge i, lanes 32-63 edge i+1 of the same row; one dword
// gather = 2 bf16 batches/lane; per 2 edges: 1 ds_read_b64 broadcast +
// ~5 VALU (2.5/edge) + 1 VMEM (halved). Rows pre-padded to even length
// (>=2) with zero-edges so the main loop (to min4 of the quad) is fully
// unmasked; masked tail <=2 iters thanks to length-balanced quads.
// Register accumulators (R6's pairing failed via LDS RMW -- avoided).
//
// Pipeline (graph-capture safe, all on `stream`):
//   1. transpose x [B,G] -> xTh [G,B] bf16 (2.56MB, fits per-XCD L2)
//   2. pass1: counting sort of 8192-edge chunks into 64-row bins (3125):
//      LDS hist[3584] -> wave-shfl scan -> LDS scatter -> coalesced dump +
//      per-chunk u32 START table.
//   3. compute: one 256-thread block per 64-row bin. Gather ~640 edges from
//      245 runs, 64-row LDS sort (padded), bitonic length-balanced quads,
//      paired PROC, halves combined via shfl_xor(32), 16KB tile epilogue.

#define WAVE 64
#define CHUNK 8192
#define RBITS 6                 // 64 rows per bin
#define BINROWS 64
#define SCAN_PAD 3584           // 512*7 >= nbin+1 = 3126
#define CAP_BIN 896             // max real edges/bin: mean 640 + ~10 sigma
#define CAP_PAD 1024            // padded capacity: 896 + 64 rows * 2

#define RL(v, i)  __builtin_amdgcn_readlane((int)(v), (i))

__device__ __forceinline__ int swz(int r, int b) {
    return (r << 6) + (b ^ (r & 63));   // tile[64][64], XOR-swizzled
}

__device__ __forceinline__ unsigned short f2bf(float f) {
    unsigned u = __float_as_uint(f);
    unsigned r = (u + 0x7fffu + ((u >> 16) & 1u)) >> 16;   // RTNE
    return (unsigned short)r;
}

__global__ void transpose64_kernel(const float* __restrict__ x,
                                   unsigned short* __restrict__ xTh, int G) {
    __shared__ float tile[64][65];
    const int t  = threadIdx.x;
    const int g0 = blockIdx.x * 64;
    {
        const int j  = t & 63;
        const int b0 = t >> 6;
        if (g0 + j < G) {
            #pragma unroll
            for (int it = 0; it < 16; ++it) {
                const int b = b0 + it * 4;
                tile[j][b] = x[(size_t)b * G + g0 + j];
            }
        }
    }
    __syncthreads();
    {
        const int b  = t & 63;
        const int j0 = t >> 6;
        #pragma unroll
        for (int it = 0; it < 16; ++it) {
            const int j = j0 + it * 4;
            if (g0 + j < G) xTh[(size_t)(g0 + j) * WAVE + b] = f2bf(tile[j][b]);
        }
    }
}

// Pass 1: per-chunk counting sort into 64-row bins. All global stores
// coalesced. Record: ((r & 63) << 15) | col.
// segtab[chunk*(nbin+1) + b] = global start of (chunk,bin) run.
__global__ __launch_bounds__(512) void pass1_kernel(
        const int* __restrict__ row, const int* __restrict__ col,
        const float* __restrict__ w, uint2* __restrict__ sedge1,
        unsigned* __restrict__ segtab, int nnz, int nbin) {
    __shared__ __align__(16) uint2 stage[CHUNK];   // 64 KB
    __shared__ int hist[SCAN_PAD];                 // 14 KB
    __shared__ int wpart[8];
    const int t    = threadIdx.x;
    const int lane = t & 63;
    const int wv   = t >> 6;
    const int e0   = blockIdx.x * CHUNK;
    const bool full = (e0 + CHUNK <= nnz);
    const int M    = full ? CHUNK : (nnz - e0);

    for (int j = t; j < SCAN_PAD; j += 512) hist[j] = 0;
    __syncthreads();

    // A) count
    if (full) {
        const int4* rv = (const int4*)(row + e0);
        #pragma unroll
        for (int k = 0; k < CHUNK / 2048; ++k) {
            const int4 r4 = rv[k * 512 + t];
            atomicAdd(&hist[r4.x >> RBITS], 1);
            atomicAdd(&hist[r4.y >> RBITS], 1);
            atomicAdd(&hist[r4.z >> RBITS], 1);
            atomicAdd(&hist[r4.w >> RBITS], 1);
        }
    } else {
        for (int k = 0; k < CHUNK / 512; ++k) {
            const int i = k * 512 + t;
            if (i < M) atomicAdd(&hist[row[e0 + i] >> RBITS], 1);
        }
    }
    __syncthreads();

    // B) scan: thread t owns bins [7t, 7t+7); wave shfl-scan + cross-wave
    {
        int c[7];
        int p = 0;
        #pragma unroll
        for (int j = 0; j < 7; ++j) { c[j] = hist[t * 7 + j]; p += c[j]; }
        int incl = p;
        #pragma unroll
        for (int d = 1; d < 64; d <<= 1) {
            const int u = __shfl_up(incl, d);
            if (lane >= d) incl += u;
        }
        if (lane == 63) wpart[wv] = incl;
        __syncthreads();
        int base = incl - p;
        #pragma unroll
        for (int ww = 0; ww < 8; ++ww)
            if (ww < wv) base += wpart[ww];
        unsigned* st = segtab + (size_t)blockIdx.x * (size_t)(nbin + 1);
        int run = base;
        #pragma unroll
        for (int j = 0; j < 7; ++j) {
            const int bj = t * 7 + j;
            hist[bj] = run;                         // scatter cursor (local)
            if (bj <= nbin) st[bj] = (unsigned)(e0 + run);
            run += c[j];
        }
    }
    __syncthreads();

    // C) scatter into LDS staging (chunk re-read is L2-hot)
    if (full) {
        const int4*   rv = (const int4*)(row + e0);
        const int4*   cv = (const int4*)(col + e0);
        const float4* wf = (const float4*)(w + e0);
        #pragma unroll
        for (int k = 0; k < CHUNK / 2048; ++k) {
            const int4   r4 = rv[k * 512 + t];
            const int4   c4 = cv[k * 512 + t];
            const float4 w4 = wf[k * 512 + t];
            {
                const int pos = atomicAdd(&hist[r4.x >> RBITS], 1);
                stage[pos] = make_uint2(((unsigned)(r4.x & 63) << 15) |
                                        (unsigned)c4.x, __float_as_uint(w4.x));
            }
            {
                const int pos = atomicAdd(&hist[r4.y >> RBITS], 1);
                stage[pos] = make_uint2(((unsigned)(r4.y & 63) << 15) |
                                        (unsigned)c4.y, __float_as_uint(w4.y));
            }
            {
                const int pos = atomicAdd(&hist[r4.z >> RBITS], 1);
                stage[pos] = make_uint2(((unsigned)(r4.z & 63) << 15) |
                                        (unsigned)c4.z, __float_as_uint(w4.z));
            }
            {
                const int pos = atomicAdd(&hist[r4.w >> RBITS], 1);
                stage[pos] = make_uint2(((unsigned)(r4.w & 63) << 15) |
                                        (unsigned)c4.w, __float_as_uint(w4.w));
            }
        }
    } else {
        for (int k = 0; k < CHUNK / 512; ++k) {
            const int i = k * 512 + t;
            if (i < M) {
                const int r = row[e0 + i];
                const int pos = atomicAdd(&hist[r >> RBITS], 1);
                stage[pos] = make_uint2(((unsigned)(r & 63) << 15) |
                                        (unsigned)col[e0 + i],
                                        __float_as_uint(w[e0 + i]));
            }
        }
    }
    __syncthreads();

    // D) coalesced contiguous dump
    {
        const uint4* sg4 = (const uint4*)stage;
        uint4* o4 = (uint4*)(sedge1 + e0);
        for (int j = t; j < (M >> 1); j += 512) o4[j] = sg4[j];
        if ((M & 1) && t == 0) sedge1[e0 + M - 1] = stage[M - 1];
    }
}

// paired, UNMASKED: half-wave takes edge ii+half; 1 dword = 2 batches
#define PROCPU(pj, alo, ahi, ii)                                              \
    {                                                                         \
        const uint2 E_ = (pj)[ii];                                            \
        const float w_ = __uint_as_float(E_.y);                               \
        const unsigned d_ = *(const unsigned*)(xb + E_.x + j4);               \
        (alo) += __uint_as_float(d_ << 16) * w_;                              \
        (ahi) += __uint_as_float(d_ & 0xffff0000u) * w_;                      \
    }

// paired, masked tail (ii may exceed nj; nj even >= 2)
#define PROCPM(pj, nj, alo, ahi, ii)                                          \
    {                                                                         \
        const int   idx_ = min((ii), (nj) - 2);                               \
        const uint2 E_   = (pj)[idx_];                                        \
        const float w_   = ((ii) < (nj)) ? __uint_as_float(E_.y) : 0.f;       \
        const unsigned d_ = *(const unsigned*)(xb + E_.x + j4);               \
        (alo) += __uint_as_float(d_ << 16) * w_;                              \
        (ahi) += __uint_as_float(d_ & 0xffff0000u) * w_;                      \
    }

// Compute: one block per 64-row bin. Gather segments -> padded LDS row-sort
// -> length-balanced paired quads -> 16KB LDS-transpose epilogue.
__global__ __launch_bounds__(256) void compute_kernel(
        const unsigned short* __restrict__ xTh,
        const uint2* __restrict__ sedge1,
        const unsigned* __restrict__ segtab,
        const float* __restrict__ bias,
        float* __restrict__ out, int S, int nchunk, int nbin) {
    __shared__ float tile[64 * 64];        // 16 KB; front doubles as eds1
    __shared__ uint2 eds2[CAP_PAD];        // 8 KB padded sorted edges
    __shared__ int   rcnt[4][BINROWS];
    __shared__ int   cur[4][BINROWS];
    __shared__ int   rstart[BINROWS], npad[BINROWS];
    __shared__ int   rord[BINROWS];        // rows by padded count (bitonic)
    __shared__ float bls[BINROWS];
    __shared__ int   spart[4];
    uint2* eds1 = (uint2*)tile;            // capacity 2048 >= CAP_BIN; dead
                                           // before first tile write

    const int t    = threadIdx.x;
    const int lane = t & 63;
    const int wv   = t >> 6;               // 0..3
    const int half = lane >> 5;            // 0: even edges, 1: odd edges
    const int j4   = (lane & 31) * 4;      // dword offset = batches 2j,2j+1

    // bijective chunked XCD swizzle: adjacent bins -> same XCD
    const int q8 = nbin >> 3, r8 = nbin & 7;
    const int xcd = (int)blockIdx.x & 7, off = (int)blockIdx.x >> 3;
    const int b = (xcd < r8 ? xcd * (q8 + 1) : r8 * (q8 + 1) + (xcd - r8) * q8)
                  + off;
    const int r0 = b << RBITS;

    if (t < BINROWS) {
        rcnt[0][t] = 0; rcnt[1][t] = 0; rcnt[2][t] = 0; rcnt[3][t] = 0;
        bls[t] = (r0 + t < S) ? bias[r0 + t] : 0.f;
    }
    // zero eds2 (pad slots must read as zero-edges)
    #pragma unroll
    for (int k = 0; k < CAP_PAD / 256; ++k)
        eds2[t + k * 256] = make_uint2(0u, 0u);

    // A) per-chunk run fetch (nchunk <= 256: one chunk per thread) + scan
    int myst = 0, myn = 0;
    if (t < nchunk) {
        const unsigned* p = segtab + (size_t)t * (size_t)(nbin + 1) + b;
        const unsigned s0 = p[0];
        myst = (int)s0; myn = (int)(p[1] - s0);
    }
    int incl = myn;
    #pragma unroll
    for (int d = 1; d < 64; d <<= 1) {
        const int u = __shfl_up(incl, d);
        if (lane >= d) incl += u;
    }
    if (lane == 63) spart[wv] = incl;
    __syncthreads();
    int base = incl - myn;
    #pragma unroll
    for (int ww = 0; ww < 4; ++ww)
        if (ww < wv) base += spart[ww];
    int M = spart[0] + spart[1] + spart[2] + spart[3];
    if (M > CAP_BIN) M = CAP_BIN;          // statistically unreachable

    // B) gather this bin's edges into LDS (order within bin irrelevant)
    for (int k = 0; k < myn; ++k) {
        const int p = base + k;
        if (p < CAP_BIN) eds1[p] = sedge1[myst + k];
    }
    __syncthreads();

    // C) row histogram (4 wave-private replicas)
    for (int i = t; i < M; i += 256)
        atomicAdd(&rcnt[wv][eds1[i].x >> 15], 1);
    __syncthreads();

    // D) scan over PADDED counts (even, >=2) + cursors + length-sort
    if (t < BINROWS) {
        const int c0 = rcnt[0][t], c1 = rcnt[1][t];
        const int c2 = rcnt[2][t], c3 = rcnt[3][t];
        const int tot = c0 + c1 + c2 + c3;
        const int pad = (tot < 2) ? 2 : ((tot + 1) & ~1);
        int inc2 = pad;
        #pragma unroll
        for (int d = 1; d < 64; d <<= 1) {
            const int u = __shfl_up(inc2, d);
            if (lane >= d) inc2 += u;
        }
        const int stt = inc2 - pad;
        rstart[t] = stt;
        npad[t]   = pad;
        cur[0][t] = stt;
        cur[1][t] = stt + c0;
        cur[2][t] = stt + c0 + c1;
        cur[3][t] = stt + c0 + c1 + c2;

        // bitonic sort rows by padded count (keys unique: (pad<<6)|row)
        int key = (pad << 6) | t;
        #pragma unroll
        for (int k = 2; k <= 64; k <<= 1) {
            #pragma unroll
            for (int j = k >> 1; j > 0; j >>= 1) {
                const int other = __shfl_xor(key, j);
                const bool lower = (lane & j) == 0;
                const bool asc   = (lane & k) == 0;   // k=64: always asc
                bool take = ((other < key) == lower);
                if (!asc) take = !take;
                key = take ? other : key;
            }
        }
        rord[t] = key & 63;    // t-th shortest row
    }
    __syncthreads();

    // E) scatter sorted-by-row; key -> byte offset of bf16 xTh row (col<<7)
    //    (same i-partition per wave as phase C -> replica consistency;
    //     pad slots beyond each row's real edges stay zero)
    for (int i = t; i < M; i += 256) {
        const uint2 e = eds1[i];
        const int r = (int)(e.x >> 15);
        const int pos = atomicAdd(&cur[wv][r], 1);
        eds2[pos] = make_uint2((e.x & 0x7fffu) << 7, e.y);
    }
    __syncthreads();

    // F) paired length-balanced quads: quad k2=qd*4+wv takes sorted rows
    //    [4*k2, 4*k2+4); half-wave pairing, 2 batches/lane
    const char* xb = (const char*)xTh;

    #pragma unroll
    for (int qd = 0; qd < 4; ++qd) {
        const int p0i = (qd * 4 + wv) * 4;
        const int rl0 = rord[p0i + 0], rl1 = rord[p0i + 1];
        const int rl2 = rord[p0i + 2], rl3 = rord[p0i + 3];
        const int n0 = npad[rl0], n1 = npad[rl1];
        const int n2 = npad[rl2], n3 = npad[rl3];
        const uint2* pp0 = eds2 + rstart[rl0] + half;
        const uint2* pp1 = eds2 + rstart[rl1] + half;
        const uint2* pp2 = eds2 + rstart[rl2] + half;
        const uint2* pp3 = eds2 + rstart[rl3] + half;
        float a0l = 0.f, a0h = 0.f, a1l = 0.f, a1h = 0.f;
        float a2l = 0.f, a2h = 0.f, a3l = 0.f, a3h = 0.f;
        const int mn = min(min(n0, n1), min(n2, n3));
        const int mm = max(max(n0, n1), max(n2, n3));
        int i = 0;
        // unmasked main (all rows valid), 8 gathers in flight via unroll-2
        for (; i + 4 <= mn; i += 4) {
            PROCPU(pp0, a0l, a0h, i)     PROCPU(pp1, a1l, a1h, i)
            PROCPU(pp2, a2l, a2h, i)     PROCPU(pp3, a3l, a3h, i)
            PROCPU(pp0, a0l, a0h, i + 2) PROCPU(pp1, a1l, a1h, i + 2)
            PROCPU(pp2, a2l, a2h, i + 2) PROCPU(pp3, a3l, a3h, i + 2)
        }
        for (; i + 2 <= mn; i += 2) {
            PROCPU(pp0, a0l, a0h, i) PROCPU(pp1, a1l, a1h, i)
            PROCPU(pp2, a2l, a2h, i) PROCPU(pp3, a3l, a3h, i)
        }
        // masked tail (<= 2 iters thanks to balancing)
        for (; i < mm; i += 2) {
            PROCPM(pp0, n0, a0l, a0h, i) PROCPM(pp1, n1, a1l, a1h, i)
            PROCPM(pp2, n2, a2l, a2h, i) PROCPM(pp3, n3, a3l, a3h, i)
        }
        // combine halves (even-edge + odd-edge partials) and write tile:
        // lane -> batch 2*(lane&31)+half; bank = batch^row -> conflict-free
        const int bcol = 2 * (lane & 31) + half;
        {
            const float cl = a0l + __shfl_xor(a0l, 32);
            const float ch = a0h + __shfl_xor(a0h, 32);
            tile[swz(rl0, bcol)] = (half ? ch : cl) + bls[rl0];
        }
        {
            const float cl = a1l + __shfl_xor(a1l, 32);
            const float ch = a1h + __shfl_xor(a1h, 32);
            tile[swz(rl1, bcol)] = (half ? ch : cl) + bls[rl1];
        }
        {
            const float cl = a2l + __shfl_xor(a2l, 32);
            const float ch = a2h + __shfl_xor(a2h, 32);
            tile[swz(rl2, bcol)] = (half ? ch : cl) + bls[rl2];
        }
        {
            const float cl = a3l + __shfl_xor(a3l, 32);
            const float ch = a3h + __shfl_xor(a3h, 32);
            tile[swz(rl3, bcol)] = (half ? ch : cl) + bls[rl3];
        }
    }
    __syncthreads();

    // G) coalesced epilogue: wave wv -> batches [wv*16, wv*16+16)
    const int srow = r0 + lane;
    #pragma unroll
    for (int k = 0; k < 16; ++k) {
        const int bb = wv * 16 + k;
        if (srow < S) out[(size_t)bb * S + srow] = tile[swz(lane, bb)];
    }
}

extern "C" void kernel_launch(void* const* d_in, const int* in_sizes, int n_in,
                              void* d_out, int out_size, void* d_ws, size_t ws_size,
                              hipStream_t stream) {
    const float* x    = (const float*)d_in[0];
    const float* W    = (const float*)d_in[1];
    const float* bias = (const float*)d_in[2];
    const int*   idx  = (const int*)d_in[3];

    const int NNZ = in_sizes[1];
    const int S   = in_sizes[2];
    const int B   = out_size / S;        // 64
    const int G   = in_sizes[0] / B;     // 20000
    const int* rowi = idx;
    const int* coli = idx + NNZ;
    float* out = (float*)d_out;

    const int nbin   = (S + BINROWS - 1) >> RBITS;        // 3125
    const int nchunk = (NNZ + CHUNK - 1) / CHUNK;         // 245 (<= 256)

    // workspace layout (256B-aligned slabs), ~21.7 MB total
    char* ws = (char*)d_ws;
    size_t o = 0;
    auto alloc = [&](size_t bytes) {
        void* p = ws + o;
        o = (o + bytes + 255) & ~(size_t)255;
        return p;
    };
    unsigned short* xTh = (unsigned short*)alloc((size_t)G * B * sizeof(unsigned short));
    uint2*    sedge1 = (uint2*)   alloc((size_t)NNZ * sizeof(uint2));
    unsigned* segtab = (unsigned*)alloc((size_t)nchunk * (size_t)(nbin + 1) *
                                        sizeof(unsigned));
    (void)ws_size; (void)n_in;

    const int tgrid = (G + 63) / 64;
    transpose64_kernel<<<tgrid, 256, 0, stream>>>(x, xTh, G);

    pass1_kernel<<<nchunk, 512, 0, stream>>>(rowi, coli, W, sedge1, segtab,
                                             NNZ, nbin);
    compute_kernel<<<nbin, 256, 0, stream>>>(xTh, sedge1, segtab, bias,
                                             out, S, nchunk, nbin);
}

// Round 11
// 155.318 us; speedup vs baseline: 1.1718x; 1.1718x over previous
//
#include <hip/hip_runtime.h>

// sparselinear: out[b*S + s] = sum_{e: row[e]==s} x[b*G + col[e]] * W[e] + bias[s]
// B=64 (== wavefront), G=20000, S=200000, NNZ=2e6.
//
// R10 post-mortem: half-wave pairing moved edge fetch into the inner loop
// as per-iteration ds_reads => latency chain (VALUBusy 25%, 90us). REVERTED.
// R7's register-broadcast quad-lockstep is bracketed as the right structure
// by 4 failed variants (R6 LDS-RMW, R8 f32, R9 occupancy, R10 paired-LDS).
// R11 = R7 with ONE change: inner-loop unroll 2 -> 4 (16 gathers in flight
// vs 8) to discriminate MLP-starvation vs issue-bound. Occupancy stays
// LDS-capped (27KB, 5 blk/CU) on purpose -- isolates the MLP axis.
//
// Pipeline (graph-capture safe, all on `stream`):
//   1. transpose x [B,G] -> xTh [G,B] bf16 (2.56MB, fits per-XCD L2)
//   2. pass1: counting sort of 8192-edge chunks into 64-row bins (3125):
//      LDS hist[3584] -> wave-shfl scan -> LDS scatter -> coalesced dump +
//      per-chunk u32 START table.
//   3. compute: one 256-thread block per 64-row bin. Gather ~640 edges from
//      245 runs, 64-row LDS sort (4-replica hist + wave scan), then
//      quad-lockstep PROC with LENGTH-BALANCED QUADS (rows bitonic-sorted
//      by count; quad k takes sorted rows 4k..4k+3 => ~5% zero-pad).
//      16KB transpose-tile epilogue overlays the staging buffer.

#define WAVE 64
#define CHUNK 8192
#define RBITS 6                 // 64 rows per bin
#define BINROWS 64
#define SCAN_PAD 3584           // 512*7 >= nbin+1 = 3126
#define CAP_BIN 896             // max edges/bin: mean 640 + ~10 sigma

#define RL(v, i)  __builtin_amdgcn_readlane((int)(v), (i))

__device__ __forceinline__ int swz(int r, int b) {
    return (r << 6) + (b ^ (r & 63));   // tile[64][64], XOR-swizzled (2-way free)
}

__device__ __forceinline__ unsigned short f2bf(float f) {
    unsigned u = __float_as_uint(f);
    unsigned r = (u + 0x7fffu + ((u >> 16) & 1u)) >> 16;   // RTNE
    return (unsigned short)r;
}

__global__ void transpose64_kernel(const float* __restrict__ x,
                                   unsigned short* __restrict__ xTh, int G) {
    __shared__ float tile[64][65];
    const int t  = threadIdx.x;
    const int g0 = blockIdx.x * 64;
    {
        const int j  = t & 63;
        const int b0 = t >> 6;
        if (g0 + j < G) {
            #pragma unroll
            for (int it = 0; it < 16; ++it) {
                const int b = b0 + it * 4;
                tile[j][b] = x[(size_t)b * G + g0 + j];
            }
        }
    }
    __syncthreads();
    {
        const int b  = t & 63;
        const int j0 = t >> 6;
        #pragma unroll
        for (int it = 0; it < 16; ++it) {
            const int j = j0 + it * 4;
            if (g0 + j < G) xTh[(size_t)(g0 + j) * WAVE + b] = f2bf(tile[j][b]);
        }
    }
}

// Pass 1: per-chunk counting sort into 64-row bins. All global stores
// coalesced. Record: ((r & 63) << 15) | col.
// segtab[chunk*(nbin+1) + b] = global start of (chunk,bin) run.
__global__ __launch_bounds__(512) void pass1_kernel(
        const int* __restrict__ row, const int* __restrict__ col,
        const float* __restrict__ w, uint2* __restrict__ sedge1,
        unsigned* __restrict__ segtab, int nnz, int nbin) {
    __shared__ __align__(16) uint2 stage[CHUNK];   // 64 KB
    __shared__ int hist[SCAN_PAD];                 // 14 KB
    __shared__ int wpart[8];
    const int t    = threadIdx.x;
    const int lane = t & 63;
    const int wv   = t >> 6;
    const int e0   = blockIdx.x * CHUNK;
    const bool full = (e0 + CHUNK <= nnz);
    const int M    = full ? CHUNK : (nnz - e0);

    for (int j = t; j < SCAN_PAD; j += 512) hist[j] = 0;
    __syncthreads();

    // A) count
    if (full) {
        const int4* rv = (const int4*)(row + e0);
        #pragma unroll
        for (int k = 0; k < CHUNK / 2048; ++k) {
            const int4 r4 = rv[k * 512 + t];
            atomicAdd(&hist[r4.x >> RBITS], 1);
            atomicAdd(&hist[r4.y >> RBITS], 1);
            atomicAdd(&hist[r4.z >> RBITS], 1);
            atomicAdd(&hist[r4.w >> RBITS], 1);
        }
    } else {
        for (int k = 0; k < CHUNK / 512; ++k) {
            const int i = k * 512 + t;
            if (i < M) atomicAdd(&hist[row[e0 + i] >> RBITS], 1);
        }
    }
    __syncthreads();

    // B) scan: thread t owns bins [7t, 7t+7); wave shfl-scan + cross-wave
    {
        int c[7];
        int p = 0;
        #pragma unroll
        for (int j = 0; j < 7; ++j) { c[j] = hist[t * 7 + j]; p += c[j]; }
        int incl = p;
        #pragma unroll
        for (int d = 1; d < 64; d <<= 1) {
            const int u = __shfl_up(incl, d);
            if (lane >= d) incl += u;
        }
        if (lane == 63) wpart[wv] = incl;
        __syncthreads();
        int base = incl - p;
        #pragma unroll
        for (int ww = 0; ww < 8; ++ww)
            if (ww < wv) base += wpart[ww];
        unsigned* st = segtab + (size_t)blockIdx.x * (size_t)(nbin + 1);
        int run = base;
        #pragma unroll
        for (int j = 0; j < 7; ++j) {
            const int bj = t * 7 + j;
            hist[bj] = run;                         // scatter cursor (local)
            if (bj <= nbin) st[bj] = (unsigned)(e0 + run);
            run += c[j];
        }
    }
    __syncthreads();

    // C) scatter into LDS staging (chunk re-read is L2-hot)
    if (full) {
        const int4*   rv = (const int4*)(row + e0);
        const int4*   cv = (const int4*)(col + e0);
        const float4* wf = (const float4*)(w + e0);
        #pragma unroll
        for (int k = 0; k < CHUNK / 2048; ++k) {
            const int4   r4 = rv[k * 512 + t];
            const int4   c4 = cv[k * 512 + t];
            const float4 w4 = wf[k * 512 + t];
            {
                const int pos = atomicAdd(&hist[r4.x >> RBITS], 1);
                stage[pos] = make_uint2(((unsigned)(r4.x & 63) << 15) |
                                        (unsigned)c4.x, __float_as_uint(w4.x));
            }
            {
                const int pos = atomicAdd(&hist[r4.y >> RBITS], 1);
                stage[pos] = make_uint2(((unsigned)(r4.y & 63) << 15) |
                                        (unsigned)c4.y, __float_as_uint(w4.y));
            }
            {
                const int pos = atomicAdd(&hist[r4.z >> RBITS], 1);
                stage[pos] = make_uint2(((unsigned)(r4.z & 63) << 15) |
                                        (unsigned)c4.z, __float_as_uint(w4.z));
            }
            {
                const int pos = atomicAdd(&hist[r4.w >> RBITS], 1);
                stage[pos] = make_uint2(((unsigned)(r4.w & 63) << 15) |
                                        (unsigned)c4.w, __float_as_uint(w4.w));
            }
        }
    } else {
        for (int k = 0; k < CHUNK / 512; ++k) {
            const int i = k * 512 + t;
            if (i < M) {
                const int r = row[e0 + i];
                const int pos = atomicAdd(&hist[r >> RBITS], 1);
                stage[pos] = make_uint2(((unsigned)(r & 63) << 15) |
                                        (unsigned)col[e0 + i],
                                        __float_as_uint(w[e0 + i]));
            }
        }
    }
    __syncthreads();

    // D) coalesced contiguous dump
    {
        const uint4* sg4 = (const uint4*)stage;
        uint4* o4 = (uint4*)(sedge1 + e0);
        for (int j = t; j < (M >> 1); j += 512) o4[j] = sg4[j];
        if ((M & 1) && t == 0) sedge1[e0 + M - 1] = stage[M - 1];
    }
}

// gather+fmac one broadcast edge for one row's accumulator
#define PROC(Er, ar, ii)                                                      \
    {                                                                         \
        const int   k_ = RL((Er).x, (ii));                                    \
        const float w_ = __int_as_float(RL((Er).y, (ii)));                    \
        const float v_ = __uint_as_float(                                     \
            (unsigned)*(const unsigned short*)(xb + k_ + lane2) << 16);       \
        (ar) += v_ * w_;                                                      \
    }

// Compute: one block per 64-row bin. Gather segments -> LDS row-sort ->
// length-balanced quad-lockstep PROC -> 16KB LDS-transpose epilogue.
__global__ __launch_bounds__(256) void compute_kernel(
        const unsigned short* __restrict__ xTh,
        const uint2* __restrict__ sedge1,
        const unsigned* __restrict__ segtab,
        const float* __restrict__ bias,
        float* __restrict__ out, int S, int nchunk, int nbin) {
    __shared__ float tile[64 * 64];        // 16 KB; front doubles as eds1
    __shared__ uint2 eds2[CAP_BIN];        // 7 KB sorted edges
    __shared__ int   rcnt[4][BINROWS];
    __shared__ int   cur[4][BINROWS];
    __shared__ int   rstart[BINROWS], rend[BINROWS];
    __shared__ int   rord[BINROWS];        // rows by edge count (bitonic)
    __shared__ float bls[BINROWS];
    __shared__ int   spart[4];
    uint2* eds1 = (uint2*)tile;            // capacity 2048 >= CAP_BIN; dead
                                           // before first tile write

    const int t    = threadIdx.x;
    const int lane = t & 63;
    const int wv   = t >> 6;               // 0..3

    // bijective chunked XCD swizzle: adjacent bins -> same XCD (L2-local
    // sedge1 runs + shared segtab lines)
    const int q8 = nbin >> 3, r8 = nbin & 7;
    const int xcd = (int)blockIdx.x & 7, off = (int)blockIdx.x >> 3;
    const int b = (xcd < r8 ? xcd * (q8 + 1) : r8 * (q8 + 1) + (xcd - r8) * q8)
                  + off;
    const int r0 = b << RBITS;

    if (t < BINROWS) {
        rcnt[0][t] = 0; rcnt[1][t] = 0; rcnt[2][t] = 0; rcnt[3][t] = 0;
        bls[t] = (r0 + t < S) ? bias[r0 + t] : 0.f;
    }

    // A) per-chunk run fetch (nchunk <= 256: one chunk per thread) + scan
    int myst = 0, myn = 0;
    if (t < nchunk) {
        const unsigned* p = segtab + (size_t)t * (size_t)(nbin + 1) + b;
        const unsigned s0 = p[0];
        myst = (int)s0; myn = (int)(p[1] - s0);
    }
    int incl = myn;
    #pragma unroll
    for (int d = 1; d < 64; d <<= 1) {
        const int u = __shfl_up(incl, d);
        if (lane >= d) incl += u;
    }
    if (lane == 63) spart[wv] = incl;
    __syncthreads();
    int base = incl - myn;
    #pragma unroll
    for (int ww = 0; ww < 4; ++ww)
        if (ww < wv) base += spart[ww];
    int M = spart[0] + spart[1] + spart[2] + spart[3];
    if (M > CAP_BIN) M = CAP_BIN;          // statistically unreachable

    // B) gather this bin's edges into LDS (order within bin irrelevant)
    for (int k = 0; k < myn; ++k) {
        const int p = base + k;
        if (p < CAP_BIN) eds1[p] = sedge1[myst + k];
    }
    __syncthreads();

    // C) row histogram (4 wave-private replicas)
    for (int i = t; i < M; i += 256)
        atomicAdd(&rcnt[wv][eds1[i].x >> 15], 1);
    __syncthreads();

    // D) 64-row scan + per-replica cursor bases + length-sort (wave 0 only)
    if (t < BINROWS) {
        const int c0 = rcnt[0][t], c1 = rcnt[1][t];
        const int c2 = rcnt[2][t], c3 = rcnt[3][t];
        const int tot = c0 + c1 + c2 + c3;
        int inc2 = tot;
        #pragma unroll
        for (int d = 1; d < 64; d <<= 1) {
            const int u = __shfl_up(inc2, d);
            if (lane >= d) inc2 += u;
        }
        const int stt = inc2 - tot;
        rstart[t] = stt;
        rend[t]   = stt + tot;
        cur[0][t] = stt;
        cur[1][t] = stt + c0;
        cur[2][t] = stt + c0 + c1;
        cur[3][t] = stt + c0 + c1 + c2;

        // bitonic sort rows by count (keys unique: (tot<<6)|row)
        int key = (tot << 6) | t;
        #pragma unroll
        for (int k = 2; k <= 64; k <<= 1) {
            #pragma unroll
            for (int j = k >> 1; j > 0; j >>= 1) {
                const int other = __shfl_xor(key, j);
                const bool lower = (lane & j) == 0;
                const bool asc   = (lane & k) == 0;   // k=64: always asc
                bool take = ((other < key) == lower);
                if (!asc) take = !take;
                key = take ? other : key;
            }
        }
        rord[t] = key & 63;    // t-th shortest row
    }
    __syncthreads();

    // E) scatter sorted-by-row; key -> byte offset of bf16 xTh row (col<<7)
    //    (same i-partition per wave as phase C -> replica consistency)
    for (int i = t; i < M; i += 256) {
        const uint2 e = eds1[i];
        const int r = (int)(e.x >> 15);
        const int pos = atomicAdd(&cur[wv][r], 1);
        eds2[pos] = make_uint2((e.x & 0x7fffu) << 7, e.y);
    }
    __syncthreads();

    // F) length-balanced quad-lockstep: quad k2=qd*4+wv takes sorted rows
    //    [4*k2, 4*k2+4); i-unroll 4 => 16 gathers in flight (R11 change)
    const char* xb = (const char*)xTh;
    const int lane2 = lane * 2;

    #pragma unroll
    for (int qd = 0; qd < 4; ++qd) {
        const int p0 = (qd * 4 + wv) * 4;
        const int rl0 = rord[p0 + 0], rl1 = rord[p0 + 1];
        const int rl2 = rord[p0 + 2], rl3 = rord[p0 + 3];
        int s0 = rstart[rl0], e0g = rend[rl0];
        int s1 = rstart[rl1], e1g = rend[rl1];
        int s2 = rstart[rl2], e2g = rend[rl2];
        int s3 = rstart[rl3], e3g = rend[rl3];
        float a0 = 0.f, a1 = 0.f, a2 = 0.f, a3 = 0.f;
        while ((s0 < e0g) || (s1 < e1g) || (s2 < e2g) || (s3 < e3g)) {
            const int m0 = min(WAVE, e0g - s0);
            const int m1 = min(WAVE, e1g - s1);
            const int m2 = min(WAVE, e2g - s2);
            const int m3 = min(WAVE, e3g - s3);
            uint2 E0 = make_uint2(0u, 0u), E1 = make_uint2(0u, 0u);
            uint2 E2 = make_uint2(0u, 0u), E3 = make_uint2(0u, 0u);
            if (lane < m0) E0 = eds2[s0 + lane];
            if (lane < m1) E1 = eds2[s1 + lane];
            if (lane < m2) E2 = eds2[s2 + lane];
            if (lane < m3) E3 = eds2[s3 + lane];
            const int mm = max(max(m0, m1), max(m2, m3));
            int i = 0;
            for (; i + 4 <= mm; i += 4) {
                PROC(E0, a0, i)     PROC(E1, a1, i)
                PROC(E2, a2, i)     PROC(E3, a3, i)
                PROC(E0, a0, i + 1) PROC(E1, a1, i + 1)
                PROC(E2, a2, i + 1) PROC(E3, a3, i + 1)
                PROC(E0, a0, i + 2) PROC(E1, a1, i + 2)
                PROC(E2, a2, i + 2) PROC(E3, a3, i + 2)
                PROC(E0, a0, i + 3) PROC(E1, a1, i + 3)
                PROC(E2, a2, i + 3) PROC(E3, a3, i + 3)
            }
            for (; i + 2 <= mm; i += 2) {
                PROC(E0, a0, i)     PROC(E1, a1, i)
                PROC(E2, a2, i)     PROC(E3, a3, i)
                PROC(E0, a0, i + 1) PROC(E1, a1, i + 1)
                PROC(E2, a2, i + 1) PROC(E3, a3, i + 1)
            }
            if (i < mm) {
                PROC(E0, a0, i) PROC(E1, a1, i) PROC(E2, a2, i) PROC(E3, a3, i)
            }
            s0 += max(m0, 0); s1 += max(m1, 0);
            s2 += max(m2, 0); s3 += max(m3, 0);
        }
        tile[swz(rl0, lane)] = a0 + bls[rl0];
        tile[swz(rl1, lane)] = a1 + bls[rl1];
        tile[swz(rl2, lane)] = a2 + bls[rl2];
        tile[swz(rl3, lane)] = a3 + bls[rl3];
    }
    __syncthreads();

    // G) coalesced epilogue: wave wv -> batches [wv*16, wv*16+16)
    const int srow = r0 + lane;
    #pragma unroll
    for (int k = 0; k < 16; ++k) {
        const int bb = wv * 16 + k;
        if (srow < S) out[(size_t)bb * S + srow] = tile[swz(lane, bb)];
    }
}

extern "C" void kernel_launch(void* const* d_in, const int* in_sizes, int n_in,
                              void* d_out, int out_size, void* d_ws, size_t ws_size,
                              hipStream_t stream) {
    const float* x    = (const float*)d_in[0];
    const float* W    = (const float*)d_in[1];
    const float* bias = (const float*)d_in[2];
    const int*   idx  = (const int*)d_in[3];

    const int NNZ = in_sizes[1];
    const int S   = in_sizes[2];
    const int B   = out_size / S;        // 64
    const int G   = in_sizes[0] / B;     // 20000
    const int* rowi = idx;
    const int* coli = idx + NNZ;
    float* out = (float*)d_out;

    const int nbin   = (S + BINROWS - 1) >> RBITS;        // 3125
    const int nchunk = (NNZ + CHUNK - 1) / CHUNK;         // 245 (<= 256)

    // workspace layout (256B-aligned slabs), ~21.7 MB total
    char* ws = (char*)d_ws;
    size_t o = 0;
    auto alloc = [&](size_t bytes) {
        void* p = ws + o;
        o = (o + bytes + 255) & ~(size_t)255;
        return p;
    };
    unsigned short* xTh = (unsigned short*)alloc((size_t)G * B * sizeof(unsigned short));
    uint2*    sedge1 = (uint2*)   alloc((size_t)NNZ * sizeof(uint2));
    unsigned* segtab = (unsigned*)alloc((size_t)nchunk * (size_t)(nbin + 1) *
                                        sizeof(unsigned));
    (void)ws_size; (void)n_in;

    const int tgrid = (G + 63) / 64;
    transpose64_kernel<<<tgrid, 256, 0, stream>>>(x, xTh, G);

    pass1_kernel<<<nchunk, 512, 0, stream>>>(rowi, coli, W, sedge1, segtab,
                                             NNZ, nbin);
    compute_kernel<<<nbin, 256, 0, stream>>>(xTh, sedge1, segtab, bias,
                                             out, S, nchunk, nbin);
}